// Round 1
// baseline (581.174 us; speedup 1.0000x reference)
//
#include <hip/hip_runtime.h>

#define D 32
#define TWO_D 64
#define B_SZ 512
#define L_SZ 64
#define OUT_N 5
#define TOTAL_NODES 65024   // 512 * (64+32+16+8+4+2+1)
#define LVL0_NODES 32768
#define ROOT_OFF   64512    // offset of level-6 (root) nodes

// ---------------------------------------------------------------------------
// K1: embedding gather. nodes[g] = embed[word_ids[g]], g in [0, 32768)
// ---------------------------------------------------------------------------
__global__ __launch_bounds__(512) void embed_kernel(
    const int* __restrict__ word_ids,
    const float* __restrict__ embed,
    float* __restrict__ nodes)
{
    int tid = blockIdx.x * 512 + threadIdx.x;   // 262144 threads
    int g   = tid >> 3;                         // node row
    int d4  = tid & 7;                          // float4 index within row
    if (g >= LVL0_NODES) return;
    int w = word_ids[g];
    const float4* src = (const float4*)(embed + (size_t)w * D);
    float4* dst = (float4*)(nodes + (size_t)g * D);
    dst[d4] = src[d4];
}

// ---------------------------------------------------------------------------
// K2: one tree level.  Output node g reads c = nodes_in[g*64 .. g*64+63]
// (children rows are adjacent), computes
//   h[k] = tanh( c^T V[k] c + (c @ W)[k] + b[k] ),  k = 0..31
// Block: 512 threads = 8 waves x 64 lanes. lane -> node (64 nodes/block),
// wave w handles k in {w, w+8, w+16, w+24} (wave-uniform -> scalar V loads).
// ---------------------------------------------------------------------------
__global__ __launch_bounds__(512) void level_kernel(
    const float* __restrict__ nodes_in,
    float* __restrict__ nodes_out,
    const float* __restrict__ V,     // (32, 64, 64) contiguous
    const float* __restrict__ W,     // (64, 32)
    const float* __restrict__ bvec)  // (32)
{
    const int lane = threadIdx.x & 63;
    const int wave = threadIdx.x >> 6;           // 0..7
    const size_t g = (size_t)blockIdx.x * 64 + lane;

    // ---- stage all 64 c-vectors of this block into padded LDS -------------
    __shared__ float sh_c[64 * 65];              // pad 65 -> conflict-free col reads
    {
        const float4* src = (const float4*)(nodes_in + (size_t)blockIdx.x * 4096);
        #pragma unroll
        for (int r = 0; r < 2; ++r) {
            int idx  = threadIdx.x + r * 512;    // 0..1023 float4s
            float4 v = src[idx];
            int node = idx >> 4;
            int pos  = (idx & 15) << 2;
            float* dstp = &sh_c[node * 65 + pos];
            dstp[0] = v.x; dstp[1] = v.y; dstp[2] = v.z; dstp[3] = v.w;
        }
    }

    // ---- own node's c in registers (constant-indexed only) ----------------
    float ce[64];
    {
        const float4* cptr = (const float4*)(nodes_in + g * 64);
        #pragma unroll
        for (int i = 0; i < 16; ++i) {
            float4 v = cptr[i];
            ce[4*i+0] = v.x; ce[4*i+1] = v.y; ce[4*i+2] = v.z; ce[4*i+3] = v.w;
        }
    }
    __syncthreads();

    const float* sh_row = &sh_c[lane * 65];

    for (int kk = 0; kk < 4; ++kk) {
        const int k = __builtin_amdgcn_readfirstlane(wave + (kk << 3));
        const float* __restrict__ Vk = V + k * 4096;   // V[k][j][l]
        const float* __restrict__ Wk = W + k;          // W[j*32 + k]
        float acc = 0.f, cw = 0.f;
        #pragma unroll 2
        for (int j = 0; j < 64; ++j) {
            const float cj = sh_row[j];                // LDS, dynamic j (ok)
            const float* __restrict__ Vr = Vk + j * 64;
            float i0 = 0.f, i1 = 0.f, i2 = 0.f, i3 = 0.f;
            #pragma unroll
            for (int l = 0; l < 64; l += 4) {          // ce[] constant-indexed
                i0 = fmaf(Vr[l+0], ce[l+0], i0);
                i1 = fmaf(Vr[l+1], ce[l+1], i1);
                i2 = fmaf(Vr[l+2], ce[l+2], i2);
                i3 = fmaf(Vr[l+3], ce[l+3], i3);
            }
            acc = fmaf(cj, (i0 + i1) + (i2 + i3), acc);
            cw  = fmaf(cj, Wk[j * 32], cw);
        }
        nodes_out[g * 32 + k] = tanhf(acc + cw + bvec[k]);
    }
}

// ---------------------------------------------------------------------------
// K3: logits + log_softmax for every node; roots copy for level-6 nodes.
// ---------------------------------------------------------------------------
__global__ __launch_bounds__(512) void out_kernel(
    const float* __restrict__ nodes,
    const float* __restrict__ Wout_w,   // (5, 32)
    const float* __restrict__ Wout_b,   // (5)
    float* __restrict__ out)
{
    int g = blockIdx.x * 512 + threadIdx.x;
    if (g >= TOTAL_NODES) return;

    float4 h4[8];
    const float4* hp = (const float4*)(nodes + (size_t)g * 32);
    #pragma unroll
    for (int i = 0; i < 8; ++i) h4[i] = hp[i];

    float logits[5];
    #pragma unroll
    for (int o = 0; o < OUT_N; ++o) {
        const float4* w = (const float4*)(Wout_w + o * 32);
        float s = 0.f;
        #pragma unroll
        for (int i = 0; i < 8; ++i) {
            float4 wv = w[i];
            s += wv.x * h4[i].x + wv.y * h4[i].y + wv.z * h4[i].z + wv.w * h4[i].w;
        }
        logits[o] = s + Wout_b[o];
    }

    float m = logits[0];
    #pragma unroll
    for (int o = 1; o < OUT_N; ++o) m = fmaxf(m, logits[o]);
    float sum = 0.f;
    #pragma unroll
    for (int o = 0; o < OUT_N; ++o) sum += expf(logits[o] - m);
    float lse = m + logf(sum);
    #pragma unroll
    for (int o = 0; o < OUT_N; ++o) out[(size_t)g * OUT_N + o] = logits[o] - lse;

    if (g >= ROOT_OFF) {
        int b = g - ROOT_OFF;
        float4* r = (float4*)(out + (size_t)TOTAL_NODES * OUT_N + (size_t)b * 32);
        #pragma unroll
        for (int i = 0; i < 8; ++i) r[i] = h4[i];
    }
}

// ---------------------------------------------------------------------------
extern "C" void kernel_launch(void* const* d_in, const int* in_sizes, int n_in,
                              void* d_out, int out_size, void* d_ws, size_t ws_size,
                              hipStream_t stream)
{
    const int*   word_ids = (const int*)  d_in[0];
    const float* embed    = (const float*)d_in[1];
    const float* V        = (const float*)d_in[2];
    const float* W        = (const float*)d_in[3];
    const float* bvec     = (const float*)d_in[4];
    const float* Wout_w   = (const float*)d_in[5];
    const float* Wout_b   = (const float*)d_in[6];
    float* out   = (float*)d_out;
    float* nodes = (float*)d_ws;          // 65024 * 32 floats = 8.3 MB

    embed_kernel<<<512, 512, 0, stream>>>(word_ids, embed, nodes);

    int off = 0;
    int n_cur = LVL0_NODES;               // rows at current level
    for (int lvl = 0; lvl < 6; ++lvl) {
        int n_next = n_cur >> 1;
        const float* in_p  = nodes + (size_t)off * D;
        float*       out_p = nodes + (size_t)(off + n_cur) * D;
        level_kernel<<<n_next / 64, 512, 0, stream>>>(in_p, out_p, V, W, bvec);
        off  += n_cur;
        n_cur = n_next;
    }

    out_kernel<<<TOTAL_NODES / 512, 512, 0, stream>>>(nodes, Wout_w, Wout_b, out);
}

// Round 2
// 147.293 us; speedup vs baseline: 3.9457x; 3.9457x over previous
//
#include <hip/hip_runtime.h>

#define D 32
#define OUT_N 5
#define TOTAL_NODES 65024   // 512 * (64+32+16+8+4+2+1)
#define LVL0_NODES 32768
#define ROOT_OFF   64512

typedef __attribute__((ext_vector_type(8))) short bf16x8;
typedef __attribute__((ext_vector_type(4))) float f32x4;
typedef __attribute__((ext_vector_type(4))) unsigned short ushort4v;

static __device__ __forceinline__ float bf2f(unsigned short u) {
    union { unsigned int i; float f; } v; v.i = ((unsigned int)u) << 16; return v.f;
}
static __device__ __forceinline__ unsigned short f2bf(float f) {
    union { float f; unsigned int i; } v; v.f = f;
    unsigned int r = v.i + 0x7fff + ((v.i >> 16) & 1);   // round-to-nearest-even
    return (unsigned short)(r >> 16);
}

// ---------------------------------------------------------------------------
// K1: embedding gather -> bf16 leaf nodes. 32768 rows x 32.
// ---------------------------------------------------------------------------
__global__ __launch_bounds__(512) void embed_kernel(
    const int* __restrict__ word_ids,
    const float* __restrict__ embed,
    unsigned short* __restrict__ nodes_b)
{
    int tid = blockIdx.x * 512 + threadIdx.x;     // 262144 threads, 4 floats each
    int g = tid >> 3, q = tid & 7;
    if (g >= LVL0_NODES) return;
    int w = word_ids[g];
    float4 v = ((const float4*)(embed + (size_t)w * D))[q];
    ushort4v o = { f2bf(v.x), f2bf(v.y), f2bf(v.z), f2bf(v.w) };
    *(ushort4v*)(nodes_b + (size_t)g * D + q * 4) = o;
}

// ---------------------------------------------------------------------------
// K2: convert V (32,64,64) fp32 -> bf16, same layout (rows = k*64+j, cols = l)
// ---------------------------------------------------------------------------
__global__ __launch_bounds__(256) void vconv_kernel(
    const float* __restrict__ V, unsigned short* __restrict__ Vb)
{
    int t = blockIdx.x * 256 + threadIdx.x;       // 32768 float4s
    if (t >= 32768) return;
    float4 v = ((const float4*)V)[t];
    ushort4v o = { f2bf(v.x), f2bf(v.y), f2bf(v.z), f2bf(v.w) };
    ((ushort4v*)Vb)[t] = o;
}

// ---------------------------------------------------------------------------
// K3: one tree level via MFMA.
// Block: 512 thr = 8 waves, 16 output nodes. Wave w owns k = 4w..4w+3.
// GEMM: D[m, (k,j)] = W[j,k] + sum_l c[m,l] * V[k,j,l]   (acc init = W trick)
// Epilogue: h[m,k] = tanh( sum_j c[m,j] * D[m,(k,j)] + b[k] )
// mfma_f32_16x16x32_bf16: A lane(row=lane&15, l=(lane>>4)*8+i)
//                         B lane(l=(lane>>4)*8+i, col=lane&15)
//                         D lane(col=lane&15, row=(lane>>4)*4+reg)
// ---------------------------------------------------------------------------
__global__ __launch_bounds__(512) void level_mfma(
    const unsigned short* __restrict__ cin,   // (N_out, 64) bf16 (child pairs)
    unsigned short* __restrict__ hout,        // (N_out, 32) bf16
    float* __restrict__ roots,                // non-null only for last level
    const unsigned short* __restrict__ Vb,    // (2048, 64) bf16
    const float* __restrict__ W,              // (64, 32) fp32
    const float* __restrict__ bias)           // (32) fp32
{
    const int tid    = threadIdx.x;
    const int lane15 = tid & 15;
    const int hi     = (tid >> 4) & 3;        // lane>>4 within wave
    const int wave   = tid >> 6;
    const int nb     = blockIdx.x * 16;       // node base

    __shared__ float sh_c[16 * 65];           // c tile fp32, padded
    for (int e = tid; e < 1024; e += 512) {
        int r = e >> 6, cidx = e & 63;
        sh_c[r * 65 + cidx] = bf2f(cin[(size_t)(nb + r) * 64 + cidx]);
    }

    // A fragments (reused for all k): c[m = lane15][l = s*32 + hi*8 + i]
    bf16x8 afr[2];
    #pragma unroll
    for (int s = 0; s < 2; ++s)
        afr[s] = *(const bf16x8*)(cin + (size_t)(nb + lane15) * 64 + s * 32 + hi * 8);
    __syncthreads();

    #pragma unroll
    for (int kk = 0; kk < 4; ++kk) {
        const int k = wave * 4 + kk;

        f32x4 acc[4];
        #pragma unroll
        for (int n = 0; n < 4; ++n) {         // acc init = W[j,k] broadcast over rows
            float wv = W[(n * 16 + lane15) * 32 + k];
            acc[n] = (f32x4){ wv, wv, wv, wv };
        }

        #pragma unroll
        for (int s = 0; s < 2; ++s) {
            #pragma unroll
            for (int n = 0; n < 4; ++n) {
                // B[l = s*32+hi*8+i][j = n*16+lane15] = Vb[(k*64+j)*64 + l]
                bf16x8 bfr = *(const bf16x8*)(Vb +
                    ((size_t)(k * 64 + n * 16 + lane15)) * 64 + s * 32 + hi * 8);
                acc[n] = __builtin_amdgcn_mfma_f32_16x16x32_bf16(afr[s], bfr, acc[n], 0, 0, 0);
            }
        }

        // epilogue: p[r] = sum_j c[row,j] * D[row,j],  row = hi*4 + r
        float p[4] = { 0.f, 0.f, 0.f, 0.f };
        #pragma unroll
        for (int n = 0; n < 4; ++n) {
            #pragma unroll
            for (int r = 0; r < 4; ++r)
                p[r] = fmaf(acc[n][r], sh_c[(hi * 4 + r) * 65 + n * 16 + lane15], p[r]);
        }
        #pragma unroll
        for (int r = 0; r < 4; ++r) {
            #pragma unroll
            for (int m = 1; m < 16; m <<= 1)
                p[r] += __shfl_xor(p[r], m, 64);
        }

        if (lane15 == 0) {
            float bk = bias[k];
            #pragma unroll
            for (int r = 0; r < 4; ++r) {
                int row = nb + hi * 4 + r;
                float h = tanhf(p[r] + bk);
                hout[(size_t)row * 32 + k] = f2bf(h);
                if (roots) roots[(size_t)row * 32 + k] = h;
            }
        }
    }
}

// ---------------------------------------------------------------------------
// K4: logits + log_softmax for every node (reads bf16 nodes).
// ---------------------------------------------------------------------------
__global__ __launch_bounds__(256) void out_kernel(
    const unsigned short* __restrict__ nodes_b,
    const float* __restrict__ Wout_w,   // (5, 32)
    const float* __restrict__ Wout_b,   // (5)
    float* __restrict__ out)
{
    int g = blockIdx.x * 256 + threadIdx.x;
    if (g >= TOTAL_NODES) return;

    float h[32];
    #pragma unroll
    for (int i = 0; i < 4; ++i) {
        bf16x8 v = *(const bf16x8*)(nodes_b + (size_t)g * 32 + i * 8);
        #pragma unroll
        for (int j = 0; j < 8; ++j) h[i * 8 + j] = bf2f((unsigned short)v[j]);
    }

    float logits[OUT_N];
    #pragma unroll
    for (int o = 0; o < OUT_N; ++o) {
        const float* w = Wout_w + o * 32;
        float s = 0.f;
        #pragma unroll
        for (int i = 0; i < 32; ++i) s = fmaf(w[i], h[i], s);
        logits[o] = s + Wout_b[o];
    }

    float m = logits[0];
    #pragma unroll
    for (int o = 1; o < OUT_N; ++o) m = fmaxf(m, logits[o]);
    float sum = 0.f;
    #pragma unroll
    for (int o = 0; o < OUT_N; ++o) sum += expf(logits[o] - m);
    float lse = m + logf(sum);
    #pragma unroll
    for (int o = 0; o < OUT_N; ++o) out[(size_t)g * OUT_N + o] = logits[o] - lse;
}

// ---------------------------------------------------------------------------
extern "C" void kernel_launch(void* const* d_in, const int* in_sizes, int n_in,
                              void* d_out, int out_size, void* d_ws, size_t ws_size,
                              hipStream_t stream)
{
    const int*   word_ids = (const int*)  d_in[0];
    const float* embed    = (const float*)d_in[1];
    const float* V        = (const float*)d_in[2];
    const float* W        = (const float*)d_in[3];
    const float* bvec     = (const float*)d_in[4];
    const float* Wout_w   = (const float*)d_in[5];
    const float* Wout_b   = (const float*)d_in[6];
    float* out = (float*)d_out;

    // workspace layout (bytes): nodes_bf16 [65024*32*2 = 4,161,536] | Vb [262,144]
    unsigned short* nodes_b = (unsigned short*)d_ws;
    unsigned short* Vb      = (unsigned short*)((char*)d_ws + (size_t)TOTAL_NODES * D * 2);

    embed_kernel<<<512, 512, 0, stream>>>(word_ids, embed, nodes_b);
    vconv_kernel<<<128, 256, 0, stream>>>(V, Vb);

    float* roots_out = out + (size_t)TOTAL_NODES * OUT_N;

    int off = 0;
    int n_cur = LVL0_NODES;
    for (int lvl = 0; lvl < 6; ++lvl) {
        int n_next = n_cur >> 1;
        const unsigned short* in_p  = nodes_b + (size_t)off * D;
        unsigned short*       out_p = nodes_b + (size_t)(off + n_cur) * D;
        float* rp = (lvl == 5) ? roots_out : nullptr;
        level_mfma<<<n_next / 16, 512, 0, stream>>>(in_p, out_p, rp, Vb, W, bvec);
        off  += n_cur;
        n_cur = n_next;
    }

    out_kernel<<<TOTAL_NODES / 256, 256, 0, stream>>>(nodes_b, Wout_w, Wout_b, out);
}

// Round 3
// 75.315 us; speedup vs baseline: 7.7165x; 1.9557x over previous
//
#include <hip/hip_runtime.h>

#define OUT_N 5
#define TOTAL_NODES 65024   // 512 * (64+32+16+8+4+2+1)
#define LVL0_NODES 32768

typedef __attribute__((ext_vector_type(8))) short bf16x8;
typedef __attribute__((ext_vector_type(4))) float f32x4;
typedef __attribute__((ext_vector_type(4))) unsigned short ushort4v;
typedef __attribute__((ext_vector_type(8))) unsigned short ushort8v;
typedef __attribute__((ext_vector_type(4))) unsigned int uint4v;

static __device__ __forceinline__ float bf2f(unsigned short u) {
    union { unsigned int i; float f; } v; v.i = ((unsigned int)u) << 16; return v.f;
}
static __device__ __forceinline__ unsigned short f2bf(float f) {
    union { float f; unsigned int i; } v; v.f = f;
    unsigned int r = v.i + 0x7fff + ((v.i >> 16) & 1);   // RNE
    return (unsigned short)(r >> 16);
}

// ---------------------------------------------------------------------------
// K1: embedding gather -> bf16 leaf nodes. 32768 rows x 32.
// ---------------------------------------------------------------------------
__global__ __launch_bounds__(512) void embed_kernel(
    const int* __restrict__ word_ids,
    const float* __restrict__ embed,
    unsigned short* __restrict__ nodes_b)
{
    int tid = blockIdx.x * 512 + threadIdx.x;     // 262144 threads, 4 floats each
    int g = tid >> 3, q = tid & 7;
    if (g >= LVL0_NODES) return;
    int w = word_ids[g];
    float4 v = ((const float4*)(embed + (size_t)w * 32))[q];
    ushort4v o = { f2bf(v.x), f2bf(v.y), f2bf(v.z), f2bf(v.w) };
    *(ushort4v*)(nodes_b + (size_t)g * 32 + q * 4) = o;
}

// ---------------------------------------------------------------------------
// K2: build B in MFMA-fragment order (bf16).
// B matrix: rows K=0..4159, cols k=0..31.
//   K < 4096 : B[K][k] = V[k*4096 + K]          (K = j*64 + l)
//   K >= 4096: B[K][k] = W[(K-4096)*32 + k]     (c@W folded into GEMM)
// Fragment layout: Bfrag[((kstep*2 + n)*64 + lane)*8 + i]
//   = B[kstep*32 + (lane>>4)*8 + i][n*16 + (lane&15)]
// => each wave-load of a fragment is 1 KB fully contiguous.
// ---------------------------------------------------------------------------
__global__ __launch_bounds__(256) void bprep_kernel(
    const float* __restrict__ V, const float* __restrict__ W,
    unsigned short* __restrict__ Bfrag)
{
    int t = blockIdx.x * 256 + threadIdx.x;       // 130*2*64 = 16640
    if (t >= 16640) return;
    int kstep = t >> 7;
    int rem   = t & 127;
    int n     = rem >> 6;
    int lane  = rem & 63;
    int hi = lane >> 4, l15 = lane & 15;
    int col = n * 16 + l15;
    int Kbase = kstep * 32 + hi * 8;
    ushort8v o;
    #pragma unroll
    for (int i = 0; i < 8; ++i) {
        int K = Kbase + i;
        float v = (K < 4096) ? V[(size_t)col * 4096 + K]
                             : W[(size_t)(K - 4096) * 32 + col];
        o[i] = f2bf(v);
    }
    *(ushort8v*)(Bfrag + (size_t)t * 8) = o;
}

// ---------------------------------------------------------------------------
// K3: one tree level, outer-product GEMM form.
//   h[m,k] = tanh( b[k] + sum_K A[m,K]*B[K,k] ),
//   A[m, j*64+l] = c[m,j]*c[m,l],  A[m, 4096+j] = c[m,j]
// Block: 256 thr = 4 waves; wave owns 16 nodes (one M-tile). N=32 -> 2 n-tiles.
// A-frag built in-register: cj (1 shfl / 2 ksteps) * lane's own l-fragment.
// mfma_f32_16x16x32_bf16: A lane(row=lane&15, K=(lane>>4)*8+i)
//                         D lane(col=lane&15, row=(lane>>4)*4+reg)
// ---------------------------------------------------------------------------
__global__ __launch_bounds__(256) void level_mfma(
    const unsigned short* __restrict__ cin,   // (N_out, 64) bf16 child pairs
    unsigned short* __restrict__ hout,        // (N_out, 32) bf16
    float* __restrict__ roots,                // non-null only for last level
    const unsigned short* __restrict__ Bfrag, // fragment-ordered B
    const float* __restrict__ bias)           // (32) fp32
{
    const int lane = threadIdx.x & 63;
    const int l15  = lane & 15;
    const int hi   = lane >> 4;
    const int wave = threadIdx.x >> 6;
    const int base = (blockIdx.x * 4 + wave) * 16;   // this wave's node base

    // lane's own c l-fragments (f32): cl[s][i] = c[base+l15][s*32 + hi*8 + i]
    float cl[2][8];
    #pragma unroll
    for (int s = 0; s < 2; ++s) {
        ushort8v v = *(const ushort8v*)(cin + (size_t)(base + l15) * 64 + s * 32 + hi * 8);
        #pragma unroll
        for (int i = 0; i < 8; ++i) cl[s][i] = bf2f(v[i]);
    }

    f32x4 acc0, acc1;
    {
        float b0 = bias[l15], b1 = bias[16 + l15];
        acc0 = (f32x4){ b0, b0, b0, b0 };
        acc1 = (f32x4){ b1, b1, b1, b1 };
    }

    const unsigned short* bp = Bfrag + (size_t)lane * 8;

    // ---- main K loop: K = j0*64 + l, fully unrolled (static reg indexing) --
    #pragma unroll
    for (int j0 = 0; j0 < 64; ++j0) {
        const int s0 = j0 >> 5, h0 = (j0 >> 3) & 3, i0 = j0 & 7;
        float cj = __shfl(cl[s0][i0], (h0 << 4) + l15, 64);   // c[row, j0]
        #pragma unroll
        for (int sA = 0; sA < 2; ++sA) {
            const int kstep = j0 * 2 + sA;
            uint4v w;
            #pragma unroll
            for (int q = 0; q < 4; ++q) {
                float lo = cj * cl[sA][2 * q];
                float hh = cj * cl[sA][2 * q + 1];
                unsigned int pk;
                asm("v_cvt_pk_bf16_f32 %0, %1, %2" : "=v"(pk) : "v"(lo), "v"(hh));
                w[q] = pk;
            }
            bf16x8 afr = __builtin_bit_cast(bf16x8, w);
            bf16x8 b0f = *(const bf16x8*)(bp + (size_t)(kstep * 2 + 0) * 512);
            bf16x8 b1f = *(const bf16x8*)(bp + (size_t)(kstep * 2 + 1) * 512);
            acc0 = __builtin_amdgcn_mfma_f32_16x16x32_bf16(afr, b0f, acc0, 0, 0, 0);
            acc1 = __builtin_amdgcn_mfma_f32_16x16x32_bf16(afr, b1f, acc1, 0, 0, 0);
        }
    }
    // ---- W tail: ksteps 128,129 ; A = raw c fragment (exact round-trip) ----
    #pragma unroll
    for (int sW = 0; sW < 2; ++sW) {
        const int kstep = 128 + sW;
        uint4v w;
        #pragma unroll
        for (int q = 0; q < 4; ++q) {
            unsigned int pk;
            asm("v_cvt_pk_bf16_f32 %0, %1, %2"
                : "=v"(pk) : "v"(cl[sW][2 * q]), "v"(cl[sW][2 * q + 1]));
            w[q] = pk;
        }
        bf16x8 afr = __builtin_bit_cast(bf16x8, w);
        bf16x8 b0f = *(const bf16x8*)(bp + (size_t)(kstep * 2 + 0) * 512);
        bf16x8 b1f = *(const bf16x8*)(bp + (size_t)(kstep * 2 + 1) * 512);
        acc0 = __builtin_amdgcn_mfma_f32_16x16x32_bf16(afr, b0f, acc0, 0, 0, 0);
        acc1 = __builtin_amdgcn_mfma_f32_16x16x32_bf16(afr, b1f, acc1, 0, 0, 0);
    }

    // ---- epilogue: tanh + store (no reduction needed; acc IS the result) --
    #pragma unroll
    for (int r = 0; r < 4; ++r) {
        const int node = base + hi * 4 + r;
        float h0v = tanhf(acc0[r]);
        float h1v = tanhf(acc1[r]);
        hout[(size_t)node * 32 + l15]      = f2bf(h0v);
        hout[(size_t)node * 32 + 16 + l15] = f2bf(h1v);
        if (roots) {
            roots[(size_t)node * 32 + l15]      = h0v;
            roots[(size_t)node * 32 + 16 + l15] = h1v;
        }
    }
}

// ---------------------------------------------------------------------------
// K4: logits + log_softmax for every node (reads bf16 nodes).
// ---------------------------------------------------------------------------
__global__ __launch_bounds__(256) void out_kernel(
    const unsigned short* __restrict__ nodes_b,
    const float* __restrict__ Wout_w,   // (5, 32)
    const float* __restrict__ Wout_b,   // (5)
    float* __restrict__ out)
{
    int g = blockIdx.x * 256 + threadIdx.x;
    if (g >= TOTAL_NODES) return;

    float h[32];
    #pragma unroll
    for (int i = 0; i < 4; ++i) {
        ushort8v v = *(const ushort8v*)(nodes_b + (size_t)g * 32 + i * 8);
        #pragma unroll
        for (int j = 0; j < 8; ++j) h[i * 8 + j] = bf2f(v[j]);
    }

    float logits[OUT_N];
    #pragma unroll
    for (int o = 0; o < OUT_N; ++o) {
        const float* w = Wout_w + o * 32;
        float s = 0.f;
        #pragma unroll
        for (int i = 0; i < 32; ++i) s = fmaf(w[i], h[i], s);
        logits[o] = s + Wout_b[o];
    }

    float m = logits[0];
    #pragma unroll
    for (int o = 1; o < OUT_N; ++o) m = fmaxf(m, logits[o]);
    float sum = 0.f;
    #pragma unroll
    for (int o = 0; o < OUT_N; ++o) sum += expf(logits[o] - m);
    float lse = m + logf(sum);
    #pragma unroll
    for (int o = 0; o < OUT_N; ++o) out[(size_t)g * OUT_N + o] = logits[o] - lse;
}

// ---------------------------------------------------------------------------
extern "C" void kernel_launch(void* const* d_in, const int* in_sizes, int n_in,
                              void* d_out, int out_size, void* d_ws, size_t ws_size,
                              hipStream_t stream)
{
    const int*   word_ids = (const int*)  d_in[0];
    const float* embed    = (const float*)d_in[1];
    const float* V        = (const float*)d_in[2];
    const float* W        = (const float*)d_in[3];
    const float* bvec     = (const float*)d_in[4];
    const float* Wout_w   = (const float*)d_in[5];
    const float* Wout_b   = (const float*)d_in[6];
    float* out = (float*)d_out;

    // ws layout: nodes_bf16 [65024*32*2 = 4,161,536 B] | Bfrag [266,240 B]
    unsigned short* nodes_b = (unsigned short*)d_ws;
    unsigned short* Bfrag   = (unsigned short*)((char*)d_ws + (size_t)TOTAL_NODES * 32 * 2);

    embed_kernel<<<512, 512, 0, stream>>>(word_ids, embed, nodes_b);
    bprep_kernel<<<65, 256, 0, stream>>>(V, W, Bfrag);

    float* roots_out = out + (size_t)TOTAL_NODES * OUT_N;

    int off = 0;
    int n_cur = LVL0_NODES;
    for (int lvl = 0; lvl < 6; ++lvl) {
        int n_next = n_cur >> 1;
        const unsigned short* in_p  = nodes_b + (size_t)off * 32;
        unsigned short*       out_p = nodes_b + (size_t)(off + n_cur) * 32;
        float* rp = (lvl == 5) ? roots_out : nullptr;
        level_mfma<<<n_next / 64, 256, 0, stream>>>(in_p, out_p, rp, Bfrag, bvec);
        off  += n_cur;
        n_cur = n_next;
    }

    out_kernel<<<TOTAL_NODES / 256, 256, 0, stream>>>(nodes_b, Wout_w, Wout_b, out);
}

// Round 4
// 47.024 us; speedup vs baseline: 12.3592x; 1.6017x over previous
//
#include <hip/hip_runtime.h>

#define OUT_N 5
#define TOTAL_NODES 65024
#define ROOTS_OFF_ELEMS (TOTAL_NODES * OUT_N)

typedef __attribute__((ext_vector_type(8))) short bf16x8;
typedef __attribute__((ext_vector_type(4))) float f32x4;
typedef __attribute__((ext_vector_type(8))) unsigned short ushort8v;
typedef __attribute__((ext_vector_type(4))) unsigned int uint4v;

constexpr int B_BYTES    = 137216;   // 67 ksteps * 2 ntiles * 64 lanes * 16B
constexpr int NODE_BYTES = 16384;    // 2 trees * 128 rows * 64B (32 bf16/row)
constexpr int SCR_BYTES  = 6144;     // 3 split-K partial slots * 2KB
constexpr int LDS_BIG    = B_BYTES + NODE_BYTES + SCR_BYTES;   // 159744
constexpr int LDS_SMALL  = NODE_BYTES + SCR_BYTES;             // 22528

static __device__ __forceinline__ float bf2f(unsigned short u) {
    union { unsigned int i; float f; } v; v.i = ((unsigned int)u) << 16; return v.f;
}
static __device__ __forceinline__ unsigned short f2bf(float f) {
    union { float f; unsigned int i; } v; v.f = f;
    unsigned int r = v.i + 0x7fff + ((v.i >> 16) & 1);   // RNE
    return (unsigned short)(r >> 16);
}
// node row R, 16B-chunk q (0..3): XOR-swizzled byte offset within node region
static __device__ __forceinline__ int node_addr(int R, int q) {
    return R * 64 + (((q ^ ((R >> 1) & 3)) & 3) << 4);
}

// ---------------------------------------------------------------------------
// bprep: symmetric-pair B table, MFMA-fragment order, bf16.
// K enumeration p = ks*32 + hi*8 + i:
//   ks<2   : diagonal, j=l=p                     -> V[k,j,j]
//   ks<64  : d=ks>>1, j=32*(ks&1)+(p&31), l=(j+d)&63 -> V[k,j,l]+V[k,l,j]
//   ks==64 : j=p&31, l=j+32                      -> V[k,j,l]+V[k,l,j]
//   ks>=65 : W rows (A=c_j)                      -> W[j,k]
// Bfrag[((ks*2+n)*64 + lane)*8 + i] = Bsym[p(ks,lane>>4,i)][n*16 + (lane&15)]
// ---------------------------------------------------------------------------
__global__ __launch_bounds__(256) void bprep_kernel(
    const float* __restrict__ V, const float* __restrict__ W,
    unsigned short* __restrict__ B)
{
    int t = blockIdx.x * 256 + threadIdx.x;
    if (t >= 8576) return;                   // 67*2*64
    int ks = t >> 7, sub = t & 127;
    int n = sub >> 6, lane = sub & 63;
    int hi = lane >> 4, l15 = lane & 15;
    int k = n * 16 + l15;
    const float* Vk = V + (size_t)k * 4096;
    ushort8v o;
    #pragma unroll
    for (int i = 0; i < 8; ++i) {
        int r5 = hi * 8 + i;
        float val;
        if (ks < 2)        { int j = 32 * ks + r5; val = Vk[j * 64 + j]; }
        else if (ks < 64)  { int d = ks >> 1; int j = 32 * (ks & 1) + r5; int l = (j + d) & 63;
                             val = Vk[j * 64 + l] + Vk[l * 64 + j]; }
        else if (ks == 64) { int j = r5; val = Vk[j * 64 + j + 32] + Vk[(j + 32) * 64 + j]; }
        else               { int j = (ks == 65) ? r5 : (32 + r5); val = W[j * 32 + k]; }
        o[i] = f2bf(val);
    }
    *(ushort8v*)(B + (size_t)t * 8) = o;
}

// ---------------------------------------------------------------------------
// One 16-row tile's K-range [k0,k1) of the symmetric outer-product GEMM.
// crot[x] = c[(x + hi*8) & 63]  -> ALL register indices compile-time.
// ---------------------------------------------------------------------------
template<int USE_LDS>
__device__ __forceinline__ void tileK(const char* smem, const unsigned short* gB,
    const float* crot, int lane, int k0, int k1, f32x4& a0, f32x4& a1)
{
    #pragma unroll
    for (int ks = 0; ks < 67; ++ks) {
        if (ks >= k0 && ks < k1) {           // wave-uniform scalar guard
            uint4v aw;
            #pragma unroll
            for (int q = 0; q < 4; ++q) {
                int i0 = 2 * q, i1 = 2 * q + 1;
                float p0, p1;
                if (ks < 2)       { p0 = crot[32*ks+i0] * crot[32*ks+i0];
                                    p1 = crot[32*ks+i1] * crot[32*ks+i1]; }
                else if (ks < 64) { const int bse = 32 * (ks & 1), d = ks >> 1;
                                    p0 = crot[bse+i0] * crot[(bse+i0+d)&63];
                                    p1 = crot[bse+i1] * crot[(bse+i1+d)&63]; }
                else if (ks == 64){ p0 = crot[i0] * crot[32+i0];
                                    p1 = crot[i1] * crot[32+i1]; }
                else if (ks == 65){ p0 = crot[i0];    p1 = crot[i1]; }
                else              { p0 = crot[32+i0]; p1 = crot[32+i1]; }
                unsigned int pk;
                asm("v_cvt_pk_bf16_f32 %0, %1, %2" : "=v"(pk) : "v"(p0), "v"(p1));
                aw[q] = pk;
            }
            bf16x8 afr = __builtin_bit_cast(bf16x8, aw);
            const int off0 = ((ks * 2 + 0) << 10) + lane * 16;
            const int off1 = ((ks * 2 + 1) << 10) + lane * 16;
            bf16x8 b0, b1;
            if constexpr (USE_LDS) {
                b0 = *(const bf16x8*)(smem + off0);
                b1 = *(const bf16x8*)(smem + off1);
            } else {
                b0 = *(const bf16x8*)((const char*)gB + off0);
                b1 = *(const bf16x8*)((const char*)gB + off1);
            }
            a0 = __builtin_amdgcn_mfma_f32_16x16x32_bf16(afr, b0, a0, 0, 0, 0);
            a1 = __builtin_amdgcn_mfma_f32_16x16x32_bf16(afr, b1, a1, 0, 0, 0);
        }
    }
}

// ---------------------------------------------------------------------------
// Mega kernel: block owns 2 trees. Stage B -> leaf gather -> 6 levels
// (split-K across waves at deep levels) -> logits/log_softmax + roots.
// Node LDS rows per tree (stride 128): L0 at 0, then 64,96,112,120,124,126.
// ---------------------------------------------------------------------------
template<int USE_LDS>
__global__ __launch_bounds__(256, 1) void tree_kernel(
    const int* __restrict__ word_ids, const float* __restrict__ embed,
    const unsigned short* __restrict__ Bg,
    const float* __restrict__ bias,
    const float* __restrict__ Wout_w, const float* __restrict__ Wout_b,
    float* __restrict__ out)
{
    extern __shared__ char smem[];
    constexpr int NODE_OFF = USE_LDS ? B_BYTES : 0;
    constexpr int SCR_OFF  = NODE_OFF + NODE_BYTES;
    const int tid = threadIdx.x;
    const int lane = tid & 63, wave = tid >> 6;
    const int l15 = lane & 15, hi = lane >> 4;

    // ---- stage B table into LDS (1KB/wave-iter, linear) -------------------
    if constexpr (USE_LDS) {
        const ushort8v* src = (const ushort8v*)Bg;
        ushort8v* dst = (ushort8v*)smem;
        #pragma unroll 2
        for (int it = 0; it < 34; ++it) {
            int idx = it * 256 + tid;
            if (idx < 8576) dst[idx] = src[idx];
        }
    }

    // ---- leaf gather: 128 rows (2 trees x 64), bf16 into swizzled LDS -----
    {
        int rr = tid >> 1, half = tid & 1;
        int wid = word_ids[blockIdx.x * 128 + rr];
        const float* ep = embed + (size_t)wid * 32 + half * 16;
        float4 va = ((const float4*)ep)[0], vb = ((const float4*)ep)[1],
               vc = ((const float4*)ep)[2], vd = ((const float4*)ep)[3];
        int R = ((rr >> 6) << 7) + (rr & 63);
        ushort8v o1, o2;
        o1[0]=f2bf(va.x); o1[1]=f2bf(va.y); o1[2]=f2bf(va.z); o1[3]=f2bf(va.w);
        o1[4]=f2bf(vb.x); o1[5]=f2bf(vb.y); o1[6]=f2bf(vb.z); o1[7]=f2bf(vb.w);
        o2[0]=f2bf(vc.x); o2[1]=f2bf(vc.y); o2[2]=f2bf(vc.z); o2[3]=f2bf(vc.w);
        o2[4]=f2bf(vd.x); o2[5]=f2bf(vd.y); o2[6]=f2bf(vd.z); o2[7]=f2bf(vd.w);
        *(ushort8v*)(smem + NODE_OFF + node_addr(R, half * 2))     = o1;
        *(ushort8v*)(smem + NODE_OFF + node_addr(R, half * 2 + 1)) = o2;
    }
    __syncthreads();

    // ---- 6 levels ---------------------------------------------------------
    for (int L = 1; L <= 6; ++L) {
        const int nL = 64 >> L, rowsT = 128 >> L, sh = 6 - L;
        const int offin  = 128 - (128 >> (L - 1));
        const int offout = 128 - (128 >> L);
        const int lw = (L >= 3) ? 2 : (L - 1);      // log2(waves per tile)
        const int wpt = 1 << lw;
        const int tile = wave >> lw;
        const int u = wave & (wpt - 1);

        int k0, k1;
        if (lw == 0)      { k0 = 0; k1 = 67; }
        else if (lw == 1) { k0 = u ? 34 : 0; k1 = u ? 67 : 34; }
        else              { k0 = (u == 0) ? 0 : (u == 1) ? 17 : (u == 2) ? 34 : 50;
                            k1 = (u == 0) ? 17 : (u == 1) ? 34 : (u == 2) ? 50 : 67; }

        // c for this lane's tile row, rotated by hi*8 (compile-time indexing)
        int row  = tile * 16 + l15;
        int rowc = (row < rowsT) ? row : 0;
        int tree = rowc >> sh;
        int ii   = rowc & (nL - 1);
        int Rc   = tree * 128 + offin + 2 * ii;     // children rows Rc, Rc+1
        float crot[64];
        #pragma unroll
        for (int t = 0; t < 8; ++t) {
            int m = (hi + t) & 7;
            int Rr = Rc + (m >> 2);
            ushort8v vv = *(const ushort8v*)(smem + NODE_OFF + node_addr(Rr, m & 3));
            #pragma unroll
            for (int e = 0; e < 8; ++e) crot[t * 8 + e] = bf2f(vv[e]);
        }

        f32x4 a0 = {0.f,0.f,0.f,0.f}, a1 = {0.f,0.f,0.f,0.f};
        tileK<USE_LDS>(smem, Bg, crot, lane, k0, k1, a0, a1);

        if (wpt > 1 && u > 0) {                      // dump split-K partial
            float* sp = (float*)(smem + SCR_OFF + (size_t)(wave - 1) * 2048 + lane * 32);
            *(f32x4*)sp = a0; *((f32x4*)sp + 1) = a1;
        }
        __syncthreads();
        if (u == 0) {
            #pragma unroll
            for (int v = 1; v < 4; ++v) {
                if (v < wpt) {
                    const float* sp = (const float*)(smem + SCR_OFF + (size_t)(wave + v - 1) * 2048 + lane * 32);
                    a0 += *(const f32x4*)sp;
                    a1 += *((const f32x4*)sp + 1);
                }
            }
            float b0 = bias[l15], b1 = bias[16 + l15];
            #pragma unroll
            for (int r = 0; r < 4; ++r) {
                int rw = tile * 16 + hi * 4 + r;
                if (rw < rowsT) {
                    float h0 = tanhf(a0[r] + b0), h1 = tanhf(a1[r] + b1);
                    int tr = rw >> sh, i2 = rw & (nL - 1);
                    int R2 = tr * 128 + offout + i2;
                    *(unsigned short*)(smem + NODE_OFF + node_addr(R2, l15 >> 3) + (l15 & 7) * 2) = f2bf(h0);
                    int c1 = 16 + l15;
                    *(unsigned short*)(smem + NODE_OFF + node_addr(R2, c1 >> 3) + (c1 & 7) * 2) = f2bf(h1);
                    if (L == 6) {                    // roots, fp32 exact
                        float* roots = out + ROOTS_OFF_ELEMS;
                        size_t rb = (size_t)(blockIdx.x * 2 + rw) * 32;
                        roots[rb + l15]      = h0;
                        roots[rb + 16 + l15] = h1;
                    }
                }
            }
        }
        __syncthreads();
    }

    // ---- logits + log_softmax for the block's 254 nodes -------------------
    if (tid < 254) {
        int tree = (tid >= 127) ? 1 : 0;
        int rr = tid - 127 * tree;
        int L, i;
        if (rr < 64)       { L = 0; i = rr; }
        else if (rr <  96) { L = 1; i = rr - 64; }
        else if (rr < 112) { L = 2; i = rr - 96; }
        else if (rr < 120) { L = 3; i = rr - 112; }
        else if (rr < 124) { L = 4; i = rr - 120; }
        else if (rr < 126) { L = 5; i = rr - 124; }
        else               { L = 6; i = 0; }
        int R = tree * 128 + rr;
        float h[32];
        #pragma unroll
        for (int q = 0; q < 4; ++q) {
            ushort8v v = *(const ushort8v*)(smem + NODE_OFF + node_addr(R, q));
            #pragma unroll
            for (int e = 0; e < 8; ++e) h[q * 8 + e] = bf2f(v[e]);
        }
        float logits[OUT_N];
        #pragma unroll
        for (int o = 0; o < OUT_N; ++o) {
            const float* w = Wout_w + o * 32;
            float s = 0.f;
            #pragma unroll
            for (int x = 0; x < 32; ++x) s = fmaf(w[x], h[x], s);
            logits[o] = s + Wout_b[o];
        }
        float m = logits[0];
        #pragma unroll
        for (int o = 1; o < OUT_N; ++o) m = fmaxf(m, logits[o]);
        float sum = 0.f;
        #pragma unroll
        for (int o = 0; o < OUT_N; ++o) sum += expf(logits[o] - m);
        float lse = m + logf(sum);
        int nLl = 64 >> L;
        size_t g = (size_t)(65536 - (65536 >> L))
                 + (size_t)(blockIdx.x * 2 + tree) * nLl + i;
        #pragma unroll
        for (int o = 0; o < OUT_N; ++o) out[g * 5 + o] = logits[o] - lse;
    }
}

// ---------------------------------------------------------------------------
extern "C" void kernel_launch(void* const* d_in, const int* in_sizes, int n_in,
                              void* d_out, int out_size, void* d_ws, size_t ws_size,
                              hipStream_t stream)
{
    const int*   word_ids = (const int*)  d_in[0];
    const float* embed    = (const float*)d_in[1];
    const float* V        = (const float*)d_in[2];
    const float* W        = (const float*)d_in[3];
    const float* bvec     = (const float*)d_in[4];
    const float* Wout_w   = (const float*)d_in[5];
    const float* Wout_b   = (const float*)d_in[6];
    float* out = (float*)d_out;

    unsigned short* Bfrag = (unsigned short*)d_ws;   // 137,216 B

    bprep_kernel<<<34, 256, 0, stream>>>(V, W, Bfrag);

    hipError_t e = hipFuncSetAttribute((const void*)&tree_kernel<1>,
                     hipFuncAttributeMaxDynamicSharedMemorySize, LDS_BIG);
    if (e == hipSuccess) {
        tree_kernel<1><<<256, 256, LDS_BIG, stream>>>(
            word_ids, embed, Bfrag, bvec, Wout_w, Wout_b, out);
    } else {
        tree_kernel<0><<<256, 256, LDS_SMALL, stream>>>(
            word_ids, embed, Bfrag, bvec, Wout_w, Wout_b, out);
    }
}